// Round 4
// baseline (255.730 us; speedup 1.0000x reference)
//
#include <hip/hip_runtime.h>
#include <hip/hip_bf16.h>

#define D_FEAT 32
#define SCAN_BLOCK 512

// ---------------------------------------------------------------------------
// K0: per-node inverse L2 norm (8 lanes/node, float4 loads).
// ---------------------------------------------------------------------------
__global__ void node_invnorm_kernel(const float* __restrict__ feat,
                                    float* __restrict__ inv_norm, int n_nodes) {
    int g = blockIdx.x * blockDim.x + threadIdx.x;
    int node = g >> 3;
    int lane = g & 7;
    if (node >= n_nodes) return;
    float4 v = reinterpret_cast<const float4*>(feat + (size_t)node * D_FEAT)[lane];
    float ss = v.x * v.x + v.y * v.y + v.z * v.z + v.w * v.w;
    #pragma unroll
    for (int m = 4; m; m >>= 1) ss += __shfl_xor(ss, m, 8);
    if (lane == 0) inv_norm[node] = 1.0f / fmaxf(sqrtf(ss), 1e-12f);
}

// ---------------------------------------------------------------------------
// K1: in-degree count.
// ---------------------------------------------------------------------------
__global__ void degree_kernel(const int* __restrict__ dst, int* __restrict__ deg,
                              int n_edges) {
    int i = blockIdx.x * blockDim.x + threadIdx.x;
    if (i < n_edges) atomicAdd(&deg[dst[i]], 1);
}

// ---------------------------------------------------------------------------
// Scan S1: per-block exclusive scan of deg; block totals to block_sums.
// ---------------------------------------------------------------------------
__global__ void scan_blocks_kernel(const int* __restrict__ deg,
                                   int* __restrict__ row_ptr,
                                   int* __restrict__ block_sums, int n) {
    __shared__ int tmp[SCAN_BLOCK];
    int i = blockIdx.x * SCAN_BLOCK + threadIdx.x;
    int v = (i < n) ? deg[i] : 0;
    tmp[threadIdx.x] = v;
    __syncthreads();
    for (int off = 1; off < SCAN_BLOCK; off <<= 1) {
        int add = (threadIdx.x >= (unsigned)off) ? tmp[threadIdx.x - off] : 0;
        __syncthreads();
        tmp[threadIdx.x] += add;
        __syncthreads();
    }
    if (i < n) row_ptr[i] = tmp[threadIdx.x] - v;  // local exclusive
    if (threadIdx.x == SCAN_BLOCK - 1) block_sums[blockIdx.x] = tmp[threadIdx.x];
}

// ---------------------------------------------------------------------------
// Scan S2: single-block exclusive scan of block_sums (nb <= 1024).
// ---------------------------------------------------------------------------
__global__ void scan_partials_kernel(int* __restrict__ block_sums, int nb) {
    __shared__ int tmp[1024];
    int t = threadIdx.x;
    int v = (t < nb) ? block_sums[t] : 0;
    tmp[t] = v;
    __syncthreads();
    for (int off = 1; off < 1024; off <<= 1) {
        int add = (t >= off) ? tmp[t - off] : 0;
        __syncthreads();
        tmp[t] += add;
        __syncthreads();
    }
    if (t < nb) block_sums[t] = tmp[t] - v;  // exclusive offsets
}

// ---------------------------------------------------------------------------
// Scan S3: add block offsets; emit final row_ptr and cursor copy.
// ---------------------------------------------------------------------------
__global__ void scan_finalize_kernel(int* __restrict__ row_ptr,
                                     int* __restrict__ cursor,
                                     const int* __restrict__ block_sums,
                                     int n, int n_edges) {
    int i = blockIdx.x * blockDim.x + threadIdx.x;
    if (i < n) {
        int r = row_ptr[i] + block_sums[i / SCAN_BLOCK];
        row_ptr[i] = r;
        cursor[i] = r;
    }
    if (i == n) row_ptr[n] = n_edges;
}

// ---------------------------------------------------------------------------
// K2: trivial CSR fill — int-only, no feature reads.
// ---------------------------------------------------------------------------
__global__ void csr_fill_kernel(const int* __restrict__ src,
                                const int* __restrict__ dst,
                                int* __restrict__ cursor,
                                int* __restrict__ csr_src, int n_edges) {
    int i = blockIdx.x * blockDim.x + threadIdx.x;
    if (i >= n_edges) return;
    int pos = atomicAdd(&cursor[dst[i]], 1);
    csr_src[pos] = src[i];
}

// ---------------------------------------------------------------------------
// K3: FUSED per-node pass. For node v (8 lanes, float4 each):
//   bn = feat[v] * inv[v]  (registers)
//   per edge: gather feat[u] ONCE -> d = dot(feat[u], bn) -> pe = exp(b*d*inv[u])
//             acc += pe * feat[u]; ssum += pe
//   out[v] = acc / ssum   (single coalesced row write, no atomics)
// 2-deep software pipeline hides the dependent csr_src -> feat[u] gather.
// ---------------------------------------------------------------------------
__global__ void fused_gather_kernel(const float* __restrict__ feat,
                                    const float* __restrict__ inv_norm,
                                    const int* __restrict__ row_ptr,
                                    const int* __restrict__ csr_src,
                                    const float* __restrict__ beta,
                                    float* __restrict__ out, int n_nodes) {
    int g = blockIdx.x * blockDim.x + threadIdx.x;
    int node = g >> 3;
    int lane = g & 7;
    if (node >= n_nodes) return;

    float bscale = beta[0];
    float4 fv = reinterpret_cast<const float4*>(feat + (size_t)node * D_FEAT)[lane];
    float invv = inv_norm[node];
    float4 bn;
    bn.x = fv.x * invv; bn.y = fv.y * invv; bn.z = fv.z * invv; bn.w = fv.w * invv;

    int start = row_ptr[node];
    int end   = row_ptr[node + 1];

    float4 acc = make_float4(0.f, 0.f, 0.f, 0.f);
    float ssum = 0.f;

    // prefetch stage 0
    int u0 = 0; float inv0 = 0.f;
    float4 a0 = make_float4(0.f, 0.f, 0.f, 0.f);
    if (start < end) {
        u0 = csr_src[start];
        inv0 = inv_norm[u0];
        a0 = reinterpret_cast<const float4*>(feat + (size_t)u0 * D_FEAT)[lane];
    }

    for (int i = start; i < end; ++i) {
        // issue next-iteration loads before consuming current
        int u1 = 0; float inv1 = 0.f;
        float4 a1 = make_float4(0.f, 0.f, 0.f, 0.f);
        if (i + 1 < end) {
            u1 = csr_src[i + 1];
            inv1 = inv_norm[u1];
            a1 = reinterpret_cast<const float4*>(feat + (size_t)u1 * D_FEAT)[lane];
        }
        float d = a0.x * bn.x;
        d = fmaf(a0.y, bn.y, d);
        d = fmaf(a0.z, bn.z, d);
        d = fmaf(a0.w, bn.w, d);
        #pragma unroll
        for (int m = 4; m; m >>= 1) d += __shfl_xor(d, m, 8);
        float pe = __expf(bscale * d * inv0);  // |arg| <= beta: max-shift skipped
        acc.x = fmaf(pe, a0.x, acc.x);
        acc.y = fmaf(pe, a0.y, acc.y);
        acc.z = fmaf(pe, a0.z, acc.z);
        acc.w = fmaf(pe, a0.w, acc.w);
        ssum += pe;
        u0 = u1; inv0 = inv1; a0 = a1;
    }

    float inv_s = (end > start) ? (1.0f / ssum) : 0.0f;
    acc.x *= inv_s; acc.y *= inv_s; acc.z *= inv_s; acc.w *= inv_s;
    reinterpret_cast<float4*>(out + (size_t)node * D_FEAT)[lane] = acc;
}

// ---------------------------------------------------------------------------
// Fallback (small ws): atomic path.
// ---------------------------------------------------------------------------
__global__ void edge_p_kernel(const float* __restrict__ feat,
                              const float* __restrict__ inv_norm,
                              const int* __restrict__ src,
                              const int* __restrict__ dst,
                              const float* __restrict__ beta,
                              float* __restrict__ p, float* __restrict__ s,
                              int n_edges) {
    int g = blockIdx.x * blockDim.x + threadIdx.x;
    int e = g >> 3;
    int lane = g & 7;
    if (e >= n_edges) return;
    int u = src[e];
    int v = dst[e];
    float4 a = reinterpret_cast<const float4*>(feat + (size_t)u * D_FEAT)[lane];
    float4 b = reinterpret_cast<const float4*>(feat + (size_t)v * D_FEAT)[lane];
    float d = a.x * b.x;
    d = fmaf(a.y, b.y, d);
    d = fmaf(a.z, b.z, d);
    d = fmaf(a.w, b.w, d);
    #pragma unroll
    for (int m = 4; m; m >>= 1) d += __shfl_xor(d, m, 8);
    if (lane == 0) {
        float pe = __expf(beta[0] * d * inv_norm[u] * inv_norm[v]);
        p[e] = pe;
        atomicAdd(&s[v], pe);
    }
}

__global__ void aggregate_atomic_kernel(const float* __restrict__ feat,
                                        const int* __restrict__ src,
                                        const int* __restrict__ dst,
                                        const float* __restrict__ p,
                                        const float* __restrict__ s,
                                        float* __restrict__ out, int n_edges) {
    int g = blockIdx.x * blockDim.x + threadIdx.x;
    int e = g >> 5;
    int lane = g & 31;
    if (e >= n_edges) return;
    int u = src[e];
    int v = dst[e];
    float w = p[e] / s[v];
    atomicAdd(&out[(size_t)v * D_FEAT + lane], feat[(size_t)u * D_FEAT + lane] * w);
}

extern "C" void kernel_launch(void* const* d_in, const int* in_sizes, int n_in,
                              void* d_out, int out_size, void* d_ws, size_t ws_size,
                              hipStream_t stream) {
    const float* feat = (const float*)d_in[0];
    const float* beta = (const float*)d_in[1];
    const int*   src  = (const int*)d_in[2];
    const int*   dst  = (const int*)d_in[3];
    float* out = (float*)d_out;

    int n_nodes = in_sizes[0] / D_FEAT;
    int n_edges = in_sizes[2];
    int nb = (n_nodes + SCAN_BLOCK - 1) / SCAN_BLOCK;

    // CSR-path workspace (4B elems):
    // inv_norm[N] | row_ptr[N+1] | cursor[N] | block_sums[1024] | csr_src[E]
    size_t need_csr = ((size_t)n_nodes * 3 + 1 + 1024 + (size_t)n_edges) * 4;
    bool use_csr = (ws_size >= need_csr) && (nb <= 1024);

    if (use_csr) {
        float* inv_norm = (float*)d_ws;
        int* row_ptr    = (int*)(inv_norm + n_nodes);       // used as deg first
        int* cursor     = row_ptr + (n_nodes + 1);
        int* block_sums = cursor + n_nodes;
        int* csr_src    = block_sums + 1024;

        hipMemsetAsync(row_ptr, 0, (size_t)(n_nodes + 1) * sizeof(int), stream);

        {
            int total = n_nodes * 8;
            node_invnorm_kernel<<<(total + 255) / 256, 256, 0, stream>>>(feat, inv_norm, n_nodes);
        }
        degree_kernel<<<(n_edges + 255) / 256, 256, 0, stream>>>(dst, row_ptr, n_edges);
        scan_blocks_kernel<<<nb, SCAN_BLOCK, 0, stream>>>(row_ptr, row_ptr, block_sums, n_nodes);
        scan_partials_kernel<<<1, 1024, 0, stream>>>(block_sums, nb);
        scan_finalize_kernel<<<(n_nodes + 1 + 255) / 256, 256, 0, stream>>>(
            row_ptr, cursor, block_sums, n_nodes, n_edges);
        csr_fill_kernel<<<(n_edges + 255) / 256, 256, 0, stream>>>(
            src, dst, cursor, csr_src, n_edges);
        {
            int total = n_nodes * 8;
            fused_gather_kernel<<<(total + 255) / 256, 256, 0, stream>>>(
                feat, inv_norm, row_ptr, csr_src, beta, out, n_nodes);
        }
    } else {
        float* inv_norm = (float*)d_ws;
        float* s_sum    = inv_norm + n_nodes;
        float* p        = s_sum + n_nodes;

        hipMemsetAsync(s_sum, 0, (size_t)n_nodes * sizeof(float), stream);
        hipMemsetAsync(out, 0, (size_t)out_size * sizeof(float), stream);

        {
            int total = n_nodes * 8;
            node_invnorm_kernel<<<(total + 255) / 256, 256, 0, stream>>>(feat, inv_norm, n_nodes);
        }
        {
            long long total = (long long)n_edges * 8;
            edge_p_kernel<<<(int)((total + 255) / 256), 256, 0, stream>>>(
                feat, inv_norm, src, dst, beta, p, s_sum, n_edges);
        }
        {
            long long total = (long long)n_edges * 32;
            aggregate_atomic_kernel<<<(int)((total + 255) / 256), 256, 0, stream>>>(
                feat, src, dst, p, s_sum, out, n_edges);
        }
    }
}

// Round 5
// 159.959 us; speedup vs baseline: 1.5987x; 1.5987x over previous
//
#include <hip/hip_runtime.h>
#include <hip/hip_bf16.h>

#define D_FEAT 32

// ---------------------------------------------------------------------------
// K0: per-node inverse L2 norm (8 lanes/node, float4 loads).
// ---------------------------------------------------------------------------
__global__ void node_invnorm_kernel(const float* __restrict__ feat,
                                    float* __restrict__ inv_norm, int n_nodes) {
    int g = blockIdx.x * blockDim.x + threadIdx.x;
    int node = g >> 3;
    int lane = g & 7;
    if (node >= n_nodes) return;
    float4 v = reinterpret_cast<const float4*>(feat + (size_t)node * D_FEAT)[lane];
    float ss = v.x * v.x + v.y * v.y + v.z * v.z + v.w * v.w;
    #pragma unroll
    for (int m = 4; m; m >>= 1) ss += __shfl_xor(ss, m, 8);
    if (lane == 0) inv_norm[node] = 1.0f / fmaxf(sqrtf(ss), 1e-12f);
}

// ---------------------------------------------------------------------------
// K1: linked-list adjacency build. next[e] write is COALESCED (sequential by
// e); only head[] (400 KB) sees random atomics. No counting sort, no scan,
// no amplified scatter.
// ---------------------------------------------------------------------------
__global__ void link_kernel(const int* __restrict__ dst,
                            int* __restrict__ head,
                            int* __restrict__ next, int n_edges) {
    int e = blockIdx.x * blockDim.x + threadIdx.x;
    if (e >= n_edges) return;
    next[e] = atomicExch(&head[dst[e]], e);
}

// ---------------------------------------------------------------------------
// K2: fused per-node chase + gather + softmax + weighted sum.
//   bn = feat[v] * inv[v] (registers)
//   walk e over v's in-edge chain:
//     u = src[e]; a = feat[u]; d = dot(a, bn); pe = exp(beta*d*inv[u])
//     acc += pe*a; ssum += pe
//   out[v] = acc / ssum  (single coalesced float4 row write; no atomics)
// Chain loads (next/src/inv) are uniform across the 8-lane group -> HW
// broadcast. next[e] is issued first each hop so the chase overlaps the
// feat-row gather + math.
// ---------------------------------------------------------------------------
__global__ void fused_chase_gather_kernel(const float* __restrict__ feat,
                                          const float* __restrict__ inv_norm,
                                          const int* __restrict__ head,
                                          const int* __restrict__ next,
                                          const int* __restrict__ src,
                                          const float* __restrict__ beta,
                                          float* __restrict__ out, int n_nodes) {
    int g = blockIdx.x * blockDim.x + threadIdx.x;
    int node = g >> 3;
    int lane = g & 7;
    if (node >= n_nodes) return;

    float bscale = beta[0];
    float4 fv = reinterpret_cast<const float4*>(feat + (size_t)node * D_FEAT)[lane];
    float invv = inv_norm[node];
    float4 bn;
    bn.x = fv.x * invv; bn.y = fv.y * invv; bn.z = fv.z * invv; bn.w = fv.w * invv;

    float4 acc = make_float4(0.f, 0.f, 0.f, 0.f);
    float ssum = 0.f;

    int e = head[node];
    while (e >= 0) {
        int en = next[e];   // issue chase first: loop-carried dep
        int u  = src[e];
        float invu = inv_norm[u];
        float4 a = reinterpret_cast<const float4*>(feat + (size_t)u * D_FEAT)[lane];
        float d = a.x * bn.x;
        d = fmaf(a.y, bn.y, d);
        d = fmaf(a.z, bn.z, d);
        d = fmaf(a.w, bn.w, d);
        #pragma unroll
        for (int m = 4; m; m >>= 1) d += __shfl_xor(d, m, 8);
        float pe = __expf(bscale * d * invu);  // |arg| <= beta: max-shift skipped
        acc.x = fmaf(pe, a.x, acc.x);
        acc.y = fmaf(pe, a.y, acc.y);
        acc.z = fmaf(pe, a.z, acc.z);
        acc.w = fmaf(pe, a.w, acc.w);
        ssum += pe;
        e = en;
    }

    float inv_s = (ssum > 0.f) ? (1.0f / ssum) : 0.0f;
    acc.x *= inv_s; acc.y *= inv_s; acc.z *= inv_s; acc.w *= inv_s;
    reinterpret_cast<float4*>(out + (size_t)node * D_FEAT)[lane] = acc;
}

// ---------------------------------------------------------------------------
// Fallback (small ws): atomic path (R1-style).
// ---------------------------------------------------------------------------
__global__ void edge_p_kernel(const float* __restrict__ feat,
                              const float* __restrict__ inv_norm,
                              const int* __restrict__ src,
                              const int* __restrict__ dst,
                              const float* __restrict__ beta,
                              float* __restrict__ p, float* __restrict__ s,
                              int n_edges) {
    int g = blockIdx.x * blockDim.x + threadIdx.x;
    int e = g >> 3;
    int lane = g & 7;
    if (e >= n_edges) return;
    int u = src[e];
    int v = dst[e];
    float4 a = reinterpret_cast<const float4*>(feat + (size_t)u * D_FEAT)[lane];
    float4 b = reinterpret_cast<const float4*>(feat + (size_t)v * D_FEAT)[lane];
    float d = a.x * b.x;
    d = fmaf(a.y, b.y, d);
    d = fmaf(a.z, b.z, d);
    d = fmaf(a.w, b.w, d);
    #pragma unroll
    for (int m = 4; m; m >>= 1) d += __shfl_xor(d, m, 8);
    if (lane == 0) {
        float pe = __expf(beta[0] * d * inv_norm[u] * inv_norm[v]);
        p[e] = pe;
        atomicAdd(&s[v], pe);
    }
}

__global__ void aggregate_atomic_kernel(const float* __restrict__ feat,
                                        const int* __restrict__ src,
                                        const int* __restrict__ dst,
                                        const float* __restrict__ p,
                                        const float* __restrict__ s,
                                        float* __restrict__ out, int n_edges) {
    int g = blockIdx.x * blockDim.x + threadIdx.x;
    int e = g >> 5;
    int lane = g & 31;
    if (e >= n_edges) return;
    int u = src[e];
    int v = dst[e];
    float w = p[e] / s[v];
    atomicAdd(&out[(size_t)v * D_FEAT + lane], feat[(size_t)u * D_FEAT + lane] * w);
}

extern "C" void kernel_launch(void* const* d_in, const int* in_sizes, int n_in,
                              void* d_out, int out_size, void* d_ws, size_t ws_size,
                              hipStream_t stream) {
    const float* feat = (const float*)d_in[0];
    const float* beta = (const float*)d_in[1];
    const int*   src  = (const int*)d_in[2];
    const int*   dst  = (const int*)d_in[3];
    float* out = (float*)d_out;

    int n_nodes = in_sizes[0] / D_FEAT;
    int n_edges = in_sizes[2];

    // Linked-list path workspace (4B elems): inv_norm[N] | head[N] | next[E]
    size_t need_ll = ((size_t)n_nodes * 2 + (size_t)n_edges) * 4;

    if (ws_size >= need_ll) {
        float* inv_norm = (float*)d_ws;
        int*   head     = (int*)(inv_norm + n_nodes);
        int*   next     = head + n_nodes;

        // head = -1 everywhere (0xFFFFFFFF)
        hipMemsetAsync(head, 0xFF, (size_t)n_nodes * sizeof(int), stream);

        {
            int total = n_nodes * 8;
            node_invnorm_kernel<<<(total + 255) / 256, 256, 0, stream>>>(
                feat, inv_norm, n_nodes);
        }
        link_kernel<<<(n_edges + 255) / 256, 256, 0, stream>>>(
            dst, head, next, n_edges);
        {
            int total = n_nodes * 8;
            fused_chase_gather_kernel<<<(total + 255) / 256, 256, 0, stream>>>(
                feat, inv_norm, head, next, src, beta, out, n_nodes);
        }
    } else {
        // Fallback: atomic path.
        float* inv_norm = (float*)d_ws;
        float* s_sum    = inv_norm + n_nodes;
        float* p        = s_sum + n_nodes;

        hipMemsetAsync(s_sum, 0, (size_t)n_nodes * sizeof(float), stream);
        hipMemsetAsync(out, 0, (size_t)out_size * sizeof(float), stream);

        {
            int total = n_nodes * 8;
            node_invnorm_kernel<<<(total + 255) / 256, 256, 0, stream>>>(
                feat, inv_norm, n_nodes);
        }
        {
            long long total = (long long)n_edges * 8;
            edge_p_kernel<<<(int)((total + 255) / 256), 256, 0, stream>>>(
                feat, inv_norm, src, dst, beta, p, s_sum, n_edges);
        }
        {
            long long total = (long long)n_edges * 32;
            aggregate_atomic_kernel<<<(int)((total + 255) / 256), 256, 0, stream>>>(
                feat, src, dst, p, s_sum, out, n_edges);
        }
    }
}

// Round 6
// 138.236 us; speedup vs baseline: 1.8500x; 1.1571x over previous
//
#include <hip/hip_runtime.h>
#include <hip/hip_bf16.h>

#define D_FEAT 32

typedef __attribute__((ext_vector_type(8))) unsigned short u16x8;
typedef __attribute__((ext_vector_type(8))) float f32x8;

// round-to-nearest-even f32 -> bf16 bits
static __device__ __forceinline__ unsigned short f2bf(float x) {
    unsigned int u = __float_as_uint(x);
    u += 0x7FFFu + ((u >> 16) & 1u);
    return (unsigned short)(u >> 16);
}
static __device__ __forceinline__ float bf2f(unsigned short b) {
    return __uint_as_float((unsigned int)b << 16);
}

// ---------------------------------------------------------------------------
// K0: per-node inverse L2 norm + bf16-compressed raw feature row.
//     8 lanes/node: float4 read, ushort4 write (row = exactly one 64B line).
// ---------------------------------------------------------------------------
__global__ void prep_kernel(const float* __restrict__ feat,
                            unsigned short* __restrict__ nfb,
                            float* __restrict__ inv_norm, int n_nodes) {
    int g = blockIdx.x * blockDim.x + threadIdx.x;
    int node = g >> 3;
    int lane = g & 7;
    if (node >= n_nodes) return;
    float4 v = reinterpret_cast<const float4*>(feat + (size_t)node * D_FEAT)[lane];
    float ss = v.x * v.x + v.y * v.y + v.z * v.z + v.w * v.w;
    #pragma unroll
    for (int m = 4; m; m >>= 1) ss += __shfl_xor(ss, m, 8);
    if (lane == 0) inv_norm[node] = 1.0f / fmaxf(sqrtf(ss), 1e-12f);
    ushort4 b;
    b.x = f2bf(v.x); b.y = f2bf(v.y); b.z = f2bf(v.z); b.w = f2bf(v.w);
    reinterpret_cast<ushort4*>(nfb + (size_t)node * D_FEAT)[lane] = b;
}

// ---------------------------------------------------------------------------
// K1a: packed linked-list build: rec[e] = {next, src}, coalesced 8B write.
//      Grid-stride for atomicExch ILP.
// ---------------------------------------------------------------------------
__global__ void link_packed_kernel(const int* __restrict__ src,
                                   const int* __restrict__ dst,
                                   int* __restrict__ head,
                                   int2* __restrict__ rec, int n_edges) {
    int stride = gridDim.x * blockDim.x;
    for (int e = blockIdx.x * blockDim.x + threadIdx.x; e < n_edges; e += stride) {
        int d = dst[e];
        int s = src[e];
        int old = atomicExch(&head[d], e);
        rec[e] = make_int2(old, s);
    }
}

// K1b: split variant (smaller ws): next[] only, chase reads input src[].
__global__ void link_split_kernel(const int* __restrict__ dst,
                                  int* __restrict__ head,
                                  int* __restrict__ next, int n_edges) {
    int stride = gridDim.x * blockDim.x;
    for (int e = blockIdx.x * blockDim.x + threadIdx.x; e < n_edges; e += stride) {
        next[e] = atomicExch(&head[dst[e]], e);
    }
}

// ---------------------------------------------------------------------------
// K2: fused chase + gather + softmax + weighted sum, bf16 rows, 4 lanes/node.
//   bn = dequant(nfb[v]) * inv[v]   (registers, 8 f32/lane)
//   per in-edge e: {next,u} from rec (or next[]+src[]), a = dequant(nfb[u]),
//     d = dot(a, bn) reduced over 4 lanes; pe = exp(beta*d*inv[u]);
//     acc += pe*a; ssum += pe
//   out[v] = acc/ssum  — two float4 stores per lane, no atomics.
// ---------------------------------------------------------------------------
template <bool PACKED>
__global__ void fused_chase_bf16_kernel(const unsigned short* __restrict__ nfb,
                                        const float* __restrict__ inv_norm,
                                        const int* __restrict__ head,
                                        const void* __restrict__ rec_or_next,
                                        const int* __restrict__ src,
                                        const float* __restrict__ beta,
                                        float* __restrict__ out, int n_nodes) {
    int g = blockIdx.x * blockDim.x + threadIdx.x;
    int node = g >> 2;
    int lane = g & 3;
    if (node >= n_nodes) return;

    const int2* rec  = (const int2*)rec_or_next;
    const int* nextp = (const int*)rec_or_next;

    float bscale = beta[0];
    float invv = inv_norm[node];
    u16x8 braw = reinterpret_cast<const u16x8*>(nfb + (size_t)node * D_FEAT)[lane];
    f32x8 bn;
    #pragma unroll
    for (int j = 0; j < 8; ++j) bn[j] = bf2f(braw[j]) * invv;

    f32x8 acc;
    #pragma unroll
    for (int j = 0; j < 8; ++j) acc[j] = 0.f;
    float ssum = 0.f;

    int e = head[node];
    while (e >= 0) {
        int en, u;
        if (PACKED) {
            int2 r = rec[e];           // one 8B random load per hop
            en = r.x; u = r.y;
        } else {
            en = nextp[e];
            u  = src[e];
        }
        float invu = inv_norm[u];
        u16x8 araw = reinterpret_cast<const u16x8*>(nfb + (size_t)u * D_FEAT)[lane];
        f32x8 a;
        float d = 0.f;
        #pragma unroll
        for (int j = 0; j < 8; ++j) {
            a[j] = bf2f(araw[j]);
            d = fmaf(a[j], bn[j], d);
        }
        d += __shfl_xor(d, 1, 4);
        d += __shfl_xor(d, 2, 4);
        float pe = __expf(bscale * d * invu);  // |arg| <= beta: max-shift skipped
        #pragma unroll
        for (int j = 0; j < 8; ++j) acc[j] = fmaf(pe, a[j], acc[j]);
        ssum += pe;
        e = en;
    }

    float inv_s = (ssum > 0.f) ? (1.0f / ssum) : 0.0f;
    float* op = out + (size_t)node * D_FEAT + lane * 8;
    float4 o0 = make_float4(acc[0] * inv_s, acc[1] * inv_s, acc[2] * inv_s, acc[3] * inv_s);
    float4 o1 = make_float4(acc[4] * inv_s, acc[5] * inv_s, acc[6] * inv_s, acc[7] * inv_s);
    reinterpret_cast<float4*>(op)[0] = o0;
    reinterpret_cast<float4*>(op)[1] = o1;
}

// ---------------------------------------------------------------------------
// Fallback (tiny ws): f32 atomic path.
// ---------------------------------------------------------------------------
__global__ void node_invnorm_kernel(const float* __restrict__ feat,
                                    float* __restrict__ inv_norm, int n_nodes) {
    int g = blockIdx.x * blockDim.x + threadIdx.x;
    int node = g >> 3;
    int lane = g & 7;
    if (node >= n_nodes) return;
    float4 v = reinterpret_cast<const float4*>(feat + (size_t)node * D_FEAT)[lane];
    float ss = v.x * v.x + v.y * v.y + v.z * v.z + v.w * v.w;
    #pragma unroll
    for (int m = 4; m; m >>= 1) ss += __shfl_xor(ss, m, 8);
    if (lane == 0) inv_norm[node] = 1.0f / fmaxf(sqrtf(ss), 1e-12f);
}

__global__ void edge_p_kernel(const float* __restrict__ feat,
                              const float* __restrict__ inv_norm,
                              const int* __restrict__ src,
                              const int* __restrict__ dst,
                              const float* __restrict__ beta,
                              float* __restrict__ p, float* __restrict__ s,
                              int n_edges) {
    int g = blockIdx.x * blockDim.x + threadIdx.x;
    int e = g >> 3;
    int lane = g & 7;
    if (e >= n_edges) return;
    int u = src[e];
    int v = dst[e];
    float4 a = reinterpret_cast<const float4*>(feat + (size_t)u * D_FEAT)[lane];
    float4 b = reinterpret_cast<const float4*>(feat + (size_t)v * D_FEAT)[lane];
    float d = a.x * b.x;
    d = fmaf(a.y, b.y, d);
    d = fmaf(a.z, b.z, d);
    d = fmaf(a.w, b.w, d);
    #pragma unroll
    for (int m = 4; m; m >>= 1) d += __shfl_xor(d, m, 8);
    if (lane == 0) {
        float pe = __expf(beta[0] * d * inv_norm[u] * inv_norm[v]);
        p[e] = pe;
        atomicAdd(&s[v], pe);
    }
}

__global__ void aggregate_atomic_kernel(const float* __restrict__ feat,
                                        const int* __restrict__ src,
                                        const int* __restrict__ dst,
                                        const float* __restrict__ p,
                                        const float* __restrict__ s,
                                        float* __restrict__ out, int n_edges) {
    int g = blockIdx.x * blockDim.x + threadIdx.x;
    int e = g >> 5;
    int lane = g & 31;
    if (e >= n_edges) return;
    int u = src[e];
    int v = dst[e];
    float w = p[e] / s[v];
    atomicAdd(&out[(size_t)v * D_FEAT + lane], feat[(size_t)u * D_FEAT + lane] * w);
}

extern "C" void kernel_launch(void* const* d_in, const int* in_sizes, int n_in,
                              void* d_out, int out_size, void* d_ws, size_t ws_size,
                              hipStream_t stream) {
    const float* feat = (const float*)d_in[0];
    const float* beta = (const float*)d_in[1];
    const int*   src  = (const int*)d_in[2];
    const int*   dst  = (const int*)d_in[3];
    float* out = (float*)d_out;

    int n_nodes = in_sizes[0] / D_FEAT;
    int n_edges = in_sizes[2];

    // ws layouts (bytes):
    //   common: nfb [N*32*2] | inv_norm [N*4] | head [N*4]
    //   packed: + rec [E*8]        split: + next [E*4]
    size_t base_bytes  = (size_t)n_nodes * D_FEAT * 2 + (size_t)n_nodes * 8;
    size_t need_packed = base_bytes + (size_t)n_edges * 8;
    size_t need_split  = base_bytes + (size_t)n_edges * 4;

    if (ws_size >= need_split) {
        bool packed = (ws_size >= need_packed);

        unsigned short* nfb = (unsigned short*)d_ws;
        float* inv_norm = (float*)(nfb + (size_t)n_nodes * D_FEAT);
        int*   head     = (int*)(inv_norm + n_nodes);
        void*  adj      = (void*)(head + n_nodes);   // rec[] or next[]

        hipMemsetAsync(head, 0xFF, (size_t)n_nodes * sizeof(int), stream);

        {
            int total = n_nodes * 8;
            prep_kernel<<<(total + 255) / 256, 256, 0, stream>>>(
                feat, nfb, inv_norm, n_nodes);
        }
        if (packed) {
            link_packed_kernel<<<1024, 256, 0, stream>>>(
                src, dst, head, (int2*)adj, n_edges);
        } else {
            link_split_kernel<<<1024, 256, 0, stream>>>(
                dst, head, (int*)adj, n_edges);
        }
        {
            int total = n_nodes * 4;
            int blocks = (total + 255) / 256;
            if (packed)
                fused_chase_bf16_kernel<true><<<blocks, 256, 0, stream>>>(
                    nfb, inv_norm, head, adj, nullptr, beta, out, n_nodes);
            else
                fused_chase_bf16_kernel<false><<<blocks, 256, 0, stream>>>(
                    nfb, inv_norm, head, adj, src, beta, out, n_nodes);
        }
    } else {
        // Fallback: atomic path.
        float* inv_norm = (float*)d_ws;
        float* s_sum    = inv_norm + n_nodes;
        float* p        = s_sum + n_nodes;

        hipMemsetAsync(s_sum, 0, (size_t)n_nodes * sizeof(float), stream);
        hipMemsetAsync(out, 0, (size_t)out_size * sizeof(float), stream);

        {
            int total = n_nodes * 8;
            node_invnorm_kernel<<<(total + 255) / 256, 256, 0, stream>>>(
                feat, inv_norm, n_nodes);
        }
        {
            long long total = (long long)n_edges * 8;
            edge_p_kernel<<<(int)((total + 255) / 256), 256, 0, stream>>>(
                feat, inv_norm, src, dst, beta, p, s_sum, n_edges);
        }
        {
            long long total = (long long)n_edges * 32;
            aggregate_atomic_kernel<<<(int)((total + 255) / 256), 256, 0, stream>>>(
                feat, src, dst, p, s_sum, out, n_edges);
        }
    }
}